// Round 10
// baseline (399.560 us; speedup 1.0000x reference)
//
#include <hip/hip_runtime.h>
#include <hip/hip_bf16.h>
#include <cstdint>

// Problem constants (from reference)
#define N_ENT  50000
#define N_EDGE 500000
#define D_IN   256
#define SPLIT  25000          // source-range phase boundary (25 MB / 12.5 MB slices)
constexpr int ETOT = N_EDGE + N_ENT;

typedef __attribute__((ext_vector_type(8))) short bfrag;   // 8 bf16 (4 VGPRs)
typedef __attribute__((ext_vector_type(4))) float f4acc;   // 4 fp32 acc
typedef __attribute__((ext_vector_type(4))) float f32x4;
typedef __attribute__((ext_vector_type(8))) short s16x8;

__device__ __forceinline__ float lrelu(float x) { return x > 0.f ? x : 0.2f * x; }
__device__ __forceinline__ float eluf(float x)  { return x > 0.f ? x : (expf(x) - 1.f); }
__device__ __forceinline__ short to_bf16(float f) {
    __hip_bfloat16 b = __float2bfloat16(f);
    return *(short*)&b;
}
// two packed bf16 -> two floats (lo = bits[15:0], hi = bits[31:16])
__device__ __forceinline__ float2 bf2_to_f32(unsigned int u) {
    float2 r;
    r.x = __uint_as_float(u << 16);
    r.y = __uint_as_float(u & 0xffff0000u);
    return r;
}

// ---------------- fused prep: LN + edge count (with low-source count) + transposes ----
//   [0,12500)        LayerNorm, 4 rows/block
//   [12500,14454)    count: histogram of edge destinations (+cnt_lo for src<SPLIT)
//   [14454,14966)    W1 [256,512] -> W1T [512,256] bf16
//   [14966,15478)    W2 [512,256] -> W2T [256,512] bf16
__global__ __launch_bounds__(256) void prep_kernel(const float* __restrict__ x,
        const float* __restrict__ lnw, const float* __restrict__ lnb,
        short* __restrict__ y, const int* __restrict__ ei, int* __restrict__ cnt,
        int* __restrict__ cnt_lo,
        const float* __restrict__ W1, short* __restrict__ W1T,
        const float* __restrict__ W2, short* __restrict__ W2T)
{
    int blk = blockIdx.x;
    if (blk < 12500) {
        int n = blk * 4 + (threadIdx.x >> 6);
        int lane = threadIdx.x & 63;
        const f32x4 v = __builtin_nontemporal_load((const f32x4*)(x + (size_t)n * D_IN + lane * 4));
        float s  = v.x + v.y + v.z + v.w;
        float sq = v.x*v.x + v.y*v.y + v.z*v.z + v.w*v.w;
        #pragma unroll
        for (int off = 1; off < 64; off <<= 1) {
            s  += __shfl_xor(s, off);
            sq += __shfl_xor(sq, off);
        }
        float mean = s * (1.f / 256.f);
        float var  = sq * (1.f / 256.f) - mean * mean;
        float rstd = rsqrtf(var + 1e-5f);
        float4 wv = *(const float4*)(lnw + lane * 4);
        float4 bv = *(const float4*)(lnb + lane * 4);
        short4 o;
        o.x = to_bf16((v.x - mean) * rstd * wv.x + bv.x);
        o.y = to_bf16((v.y - mean) * rstd * wv.y + bv.y);
        o.z = to_bf16((v.z - mean) * rstd * wv.z + bv.z);
        o.w = to_bf16((v.w - mean) * rstd * wv.w + bv.w);
        *(short4*)(y + (size_t)n * D_IN + lane * 4) = o;
    } else if (blk < 14454) {
        int e = (blk - 12500) * 256 + threadIdx.x;
        if (e < N_EDGE) {
            int s = ei[e];
            int d = ei[N_EDGE + e];
            atomicAdd(&cnt[d], 1);
            if (s < SPLIT) atomicAdd(&cnt_lo[d], 1);
        }
    } else if (blk < 14966) {
        int i = (blk - 14454) * 256 + threadIdx.x;     // < 131072, W1[256,512]
        int r = i >> 9, c = i & 511;
        W1T[c * 256 + r] = to_bf16(W1[i]);
    } else {
        int i = (blk - 14966) * 256 + threadIdx.x;     // < 131072, W2[512,256]
        int r = i >> 8, c = i & 255;
        W2T[c * 512 + r] = to_bf16(W2[i]);
    }
}

// ---------------- bf16 MFMA GEMM + fused dots + optional CSR-fill tail ----------------
// C[M,NN] = A[M,KK] @ BT[NN,KK]^T, bf16 out. 128x128 tile, BK=32, 4 waves. 1D grid:
// blocks [0,nGemm) do GEMM; blocks >= nGemm scatter edges into the source-range-
// partitioned CSR (row = [srcs<SPLIT ..., srcs>=SPLIT ...]). CH: 0=none,
// 64=per-head plain store, 256=atomic single-head.
template<int NN, int KK, int CH, bool DO_FILL>
__global__ __launch_bounds__(256) void gemm_mfma(const short* __restrict__ A,
        const short* __restrict__ BT, short* __restrict__ C,
        const float* __restrict__ att_s, const float* __restrict__ att_d,
        float* __restrict__ a_s, float* __restrict__ a_d, int M, int nGemm,
        const int* __restrict__ ei, const int* __restrict__ row_start,
        const int* __restrict__ cnt_lo, int* __restrict__ cur_lo,
        int* __restrict__ cur_hi, int* __restrict__ csr_src)
{
    constexpr int GX = NN / 128;
    __shared__ short As[128 * 32];
    __shared__ short Bs[128 * 32];

    if (DO_FILL && (int)blockIdx.x >= nGemm) {
        int e = ((int)blockIdx.x - nGemm) * 256 + threadIdx.x;
        if (e < N_EDGE) {
            int s = ei[e];
            int d = ei[N_EDGE + e];
            int base = row_start[d];
            if (s < SPLIT) {
                int pos = atomicAdd(&cur_lo[d], 1);
                csr_src[base + pos] = s;
            } else {
                int pos = atomicAdd(&cur_hi[d], 1);
                csr_src[base + cnt_lo[d] + pos] = s;
            }
        }
        return;
    }

    const int tid  = threadIdx.x;
    const int w    = tid >> 6;
    const int l    = tid & 63;
    const int wm   = w >> 1, wn = w & 1;
    const int m0   = ((int)blockIdx.x / GX) * 128;
    const int n0   = ((int)blockIdx.x % GX) * 128;
    const int quad = l >> 4;
    const int ln16 = l & 15;
    const int rl   = l >> 2;   // staging: row within 16-row issue group
    const int cs   = l & 3;    // staging: chunk slot

    f4acc acc[4][4];
    #pragma unroll
    for (int i = 0; i < 4; ++i)
        #pragma unroll
        for (int j = 0; j < 4; ++j)
            acc[i][j] = (f4acc){0.f, 0.f, 0.f, 0.f};

    for (int k0 = 0; k0 < KK; k0 += 32) {
        __syncthreads();
        #pragma unroll
        for (int tt = 0; tt < 2; ++tt) {
            int t   = w * 2 + tt;          // issue id 0..7 (16 rows each)
            int row = t * 16 + rl;         // local row 0..127
            int ca  = cs ^ ((row >> 1) & 3);
            const short* ga = A + (size_t)(m0 + row) * KK + k0 + ca * 8;
            __builtin_amdgcn_global_load_lds(
                (const __attribute__((address_space(1))) unsigned int*)ga,
                (__attribute__((address_space(3))) unsigned int*)&As[t * 512], 16, 0, 0);
            const short* gb = BT + (size_t)(n0 + row) * KK + k0 + ca * 8;
            __builtin_amdgcn_global_load_lds(
                (const __attribute__((address_space(1))) unsigned int*)gb,
                (__attribute__((address_space(3))) unsigned int*)&Bs[t * 512], 16, 0, 0);
        }
        __syncthreads();
        bfrag af[4], bf[4];
        #pragma unroll
        for (int i = 0; i < 4; ++i) {
            int r = wm * 64 + i * 16 + ln16;           // A row (m)
            af[i] = *(const bfrag*)&As[r * 32 + (quad ^ ((r >> 1) & 3)) * 8];
            int rn = wn * 64 + i * 16 + ln16;          // B col (n)
            bf[i] = *(const bfrag*)&Bs[rn * 32 + (quad ^ ((rn >> 1) & 3)) * 8];
        }
        #pragma unroll
        for (int i = 0; i < 4; ++i)
            #pragma unroll
            for (int j = 0; j < 4; ++j)
                acc[i][j] = __builtin_amdgcn_mfma_f32_16x16x32_bf16(af[i], bf[j], acc[i][j], 0, 0, 0);
    }

    float as_c[4], ad_c[4];
    if constexpr (CH > 0) {
        #pragma unroll
        for (int j = 0; j < 4; ++j) {
            int gc = n0 + wn * 64 + j * 16 + ln16;
            as_c[j] = att_s[gc];
            ad_c[j] = att_d[gc];
        }
    }
    const int hh = (n0 + wn * 64) >> 6;    // head index when CH=64

    // epilogue: C/D layout col=lane&15, row=quad*4+reg; bf16 store (+dots)
    #pragma unroll
    for (int i = 0; i < 4; ++i) {
        #pragma unroll
        for (int p = 0; p < 4; ++p) {
            int gr = m0 + wm * 64 + i * 16 + quad * 4 + p;
            float ps = 0.f, pd = 0.f;
            if constexpr (CH > 0) {
                #pragma unroll
                for (int j = 0; j < 4; ++j) {
                    float c = acc[i][j][p];
                    ps = fmaf(c, as_c[j], ps);
                    pd = fmaf(c, ad_c[j], pd);
                }
                #pragma unroll
                for (int off = 1; off < 16; off <<= 1) {
                    ps += __shfl_xor(ps, off);
                    pd += __shfl_xor(pd, off);
                }
            }
            if (gr < M) {
                #pragma unroll
                for (int j = 0; j < 4; ++j) {
                    int gc = n0 + wn * 64 + j * 16 + ln16;
                    C[(size_t)gr * NN + gc] = to_bf16(acc[i][j][p]);
                }
                if constexpr (CH == 64) {
                    if (ln16 == 0) {
                        a_s[(size_t)gr * (NN / 64) + hh] = ps;
                        a_d[(size_t)gr * (NN / 64) + hh] = pd;
                    }
                } else if constexpr (CH == 256) {
                    if (ln16 == 0) {
                        unsafeAtomicAdd(&a_s[gr], ps);
                        unsafeAtomicAdd(&a_d[gr], pd);
                    }
                }
            }
        }
    }
}

// ---------------- CSR alloc: exclusive scan of counts ----------------
__global__ __launch_bounds__(256) void alloc_kernel(const int* __restrict__ cnt,
        int* __restrict__ row_start, int* __restrict__ cursor)
{
    int d = blockIdx.x * 256 + threadIdx.x;
    int lane = threadIdx.x & 63;
    int c = (d < N_ENT) ? cnt[d] : 0;
    int inc = c;
    #pragma unroll
    for (int off = 1; off < 64; off <<= 1) {
        int nb = __shfl_up(inc, off);
        if (lane >= off) inc += nb;
    }
    int waveTotal = __shfl(inc, 63);
    int base = 0;
    if (lane == 63) base = atomicAdd(cursor, waveTotal);
    base = __shfl(base, 63);
    if (d < N_ENT) row_start[d] = base + inc - c;
}

// ---------------- aggr1 range helper: full wave per edge, F=512 ----------------
__device__ __forceinline__ void aggr1_range(const int* __restrict__ csr_src, int rs,
        int lo, int hi, const short* __restrict__ feat, const float* __restrict__ a_s,
        int h, float adh, int f0, float& den, float acc[8])
{
    int i = lo;
    for (; i + 4 <= hi; i += 4) {
        int   sv[4];
        float ev[4];
        uint4 rv[4];
        #pragma unroll
        for (int u = 0; u < 4; ++u) sv[u] = csr_src[rs + i + u];
        #pragma unroll
        for (int u = 0; u < 4; ++u) ev[u] = a_s[sv[u] * 8 + h];
        #pragma unroll
        for (int u = 0; u < 4; ++u) rv[u] = *(const uint4*)(feat + (size_t)sv[u] * 512 + f0);
        #pragma unroll
        for (int u = 0; u < 4; ++u) {
            float p = __expf(lrelu(ev[u] + adh));
            den += p;
            float2 t0 = bf2_to_f32(rv[u].x), t1 = bf2_to_f32(rv[u].y);
            float2 t2 = bf2_to_f32(rv[u].z), t3 = bf2_to_f32(rv[u].w);
            acc[0] += p * t0.x; acc[1] += p * t0.y; acc[2] += p * t1.x; acc[3] += p * t1.y;
            acc[4] += p * t2.x; acc[5] += p * t2.y; acc[6] += p * t3.x; acc[7] += p * t3.y;
        }
    }
    for (; i < hi; ++i) {
        int s = csr_src[rs + i];
        float p = __expf(lrelu(a_s[s * 8 + h] + adh));
        den += p;
        uint4 rv = *(const uint4*)(feat + (size_t)s * 512 + f0);
        float2 t0 = bf2_to_f32(rv.x), t1 = bf2_to_f32(rv.y);
        float2 t2 = bf2_to_f32(rv.z), t3 = bf2_to_f32(rv.w);
        acc[0] += p * t0.x; acc[1] += p * t0.y; acc[2] += p * t1.x; acc[3] += p * t1.y;
        acc[4] += p * t2.x; acc[5] += p * t2.y; acc[6] += p * t3.x; acc[7] += p * t3.y;
    }
}

// ---------------- conv1 aggregation: wave per dst, two source-range phases -------
// H=8, C=64, F=512. lane owns 8 contiguous bf16 (16 B); head h = lane>>3.
// Phase A: sources < SPLIT (25 MB table slice), phase B: rest — all resident
// blocks sweep A then B, bounding the chip-wide active read set.
__global__ __launch_bounds__(256) void aggr1_kernel(const int* __restrict__ csr_src,
        const int* __restrict__ row_start, const int* __restrict__ cnt,
        const int* __restrict__ cnt_lo,
        const short* __restrict__ feat, const float* __restrict__ a_s,
        const float* __restrict__ a_d, const float* __restrict__ bias,
        short* __restrict__ out)
{
    int d = blockIdx.x * 4 + (threadIdx.x >> 6);
    if (d >= N_ENT) return;
    int lane = threadIdx.x & 63;
    int f0 = lane * 8;
    int h = lane >> 3;
    int rs = row_start[d];
    int n = cnt[d];
    int nLo = cnt_lo[d];
    float adh = a_d[d * 8 + h];

    float den = 0.f;
    float acc[8] = {0.f, 0.f, 0.f, 0.f, 0.f, 0.f, 0.f, 0.f};
    // self loop
    {
        float p = __expf(lrelu(a_s[d * 8 + h] + adh));
        den += p;
        uint4 rv = *(const uint4*)(feat + (size_t)d * 512 + f0);
        float2 t0 = bf2_to_f32(rv.x), t1 = bf2_to_f32(rv.y);
        float2 t2 = bf2_to_f32(rv.z), t3 = bf2_to_f32(rv.w);
        acc[0] += p * t0.x; acc[1] += p * t0.y; acc[2] += p * t1.x; acc[3] += p * t1.y;
        acc[4] += p * t2.x; acc[5] += p * t2.y; acc[6] += p * t3.x; acc[7] += p * t3.y;
    }
    aggr1_range(csr_src, rs, 0, nLo, feat, a_s, h, adh, f0, den, acc);   // phase A
    aggr1_range(csr_src, rs, nLo, n, feat, a_s, h, adh, f0, den, acc);   // phase B

    float inv = 1.f / den;
    float4 b0 = *(const float4*)(bias + f0);
    float4 b1 = *(const float4*)(bias + f0 + 4);
    s16x8 o;
    o[0] = to_bf16(eluf(acc[0] * inv + b0.x)); o[1] = to_bf16(eluf(acc[1] * inv + b0.y));
    o[2] = to_bf16(eluf(acc[2] * inv + b0.z)); o[3] = to_bf16(eluf(acc[3] * inv + b0.w));
    o[4] = to_bf16(eluf(acc[4] * inv + b1.x)); o[5] = to_bf16(eluf(acc[5] * inv + b1.y));
    o[6] = to_bf16(eluf(acc[6] * inv + b1.z)); o[7] = to_bf16(eluf(acc[7] * inv + b1.w));
    __builtin_nontemporal_store(o, (s16x8*)(out + (size_t)d * 512 + f0));
}

// ---------------- aggr2 range helper: half-wave per edge, F=256, unroll x4 -------
__device__ __forceinline__ void aggr2_range(const int* __restrict__ csr_src, int rs,
        int lo, int hi, const short* __restrict__ feat, const float* __restrict__ a_s,
        float adh, int f0, int half, float& den, float acc[8])
{
    int i = lo;
    for (; i + 8 <= hi; i += 8) {          // 8 edges per iter (4 per half)
        int   sv[4];
        float av[4];
        uint4 rv[4];
        #pragma unroll
        for (int u = 0; u < 4; ++u) sv[u] = csr_src[rs + i + 2 * u + half];
        #pragma unroll
        for (int u = 0; u < 4; ++u) av[u] = a_s[sv[u]];
        #pragma unroll
        for (int u = 0; u < 4; ++u) rv[u] = *(const uint4*)(feat + (size_t)sv[u] * 256 + f0);
        #pragma unroll
        for (int u = 0; u < 4; ++u) {
            float p = __expf(lrelu(av[u] + adh));
            den += p;
            float2 t0 = bf2_to_f32(rv[u].x), t1 = bf2_to_f32(rv[u].y);
            float2 t2 = bf2_to_f32(rv[u].z), t3 = bf2_to_f32(rv[u].w);
            acc[0] += p * t0.x; acc[1] += p * t0.y; acc[2] += p * t1.x; acc[3] += p * t1.y;
            acc[4] += p * t2.x; acc[5] += p * t2.y; acc[6] += p * t3.x; acc[7] += p * t3.y;
        }
    }
    for (; i + 2 <= hi; i += 2) {          // 2 edges (1 per half)
        int s = csr_src[rs + i + half];
        float av = a_s[s];
        uint4 rv = *(const uint4*)(feat + (size_t)s * 256 + f0);
        float p = __expf(lrelu(av + adh));
        den += p;
        float2 t0 = bf2_to_f32(rv.x), t1 = bf2_to_f32(rv.y);
        float2 t2 = bf2_to_f32(rv.z), t3 = bf2_to_f32(rv.w);
        acc[0] += p * t0.x; acc[1] += p * t0.y; acc[2] += p * t1.x; acc[3] += p * t1.y;
        acc[4] += p * t2.x; acc[5] += p * t2.y; acc[6] += p * t3.x; acc[7] += p * t3.y;
    }
    if (i < hi) {                          // single leftover edge (half 0 only)
        bool valid = (half == 0);
        int s = valid ? csr_src[rs + i] : 0;
        float av = a_s[s];
        uint4 rv = *(const uint4*)(feat + (size_t)s * 256 + f0);
        float p = valid ? __expf(lrelu(av + adh)) : 0.f;
        den += p;
        float2 t0 = bf2_to_f32(rv.x), t1 = bf2_to_f32(rv.y);
        float2 t2 = bf2_to_f32(rv.z), t3 = bf2_to_f32(rv.w);
        acc[0] += p * t0.x; acc[1] += p * t0.y; acc[2] += p * t1.x; acc[3] += p * t1.y;
        acc[4] += p * t2.x; acc[5] += p * t2.y; acc[6] += p * t3.x; acc[7] += p * t3.y;
    }
}

// ---------------- conv2 aggregation: wave per dst, half-wave per edge, 2 phases --
__global__ __launch_bounds__(256) void aggr2_kernel(const int* __restrict__ csr_src,
        const int* __restrict__ row_start, const int* __restrict__ cnt,
        const int* __restrict__ cnt_lo,
        const short* __restrict__ feat, const float* __restrict__ a_s,
        const float* __restrict__ a_d, const float* __restrict__ bias,
        float* __restrict__ out)
{
    int d = blockIdx.x * 4 + (threadIdx.x >> 6);
    if (d >= N_ENT) return;
    int lane = threadIdx.x & 63;
    int half = lane >> 5;
    int li   = lane & 31;
    int f0   = li * 8;
    int rs = row_start[d];
    int n = cnt[d];
    int nLo = cnt_lo[d];
    float adh = a_d[d];

    float den = 0.f;
    float acc[8] = {0.f, 0.f, 0.f, 0.f, 0.f, 0.f, 0.f, 0.f};
    // self loop (half 0 only accumulates)
    {
        float p = (half == 0) ? __expf(lrelu(a_s[d] + adh)) : 0.f;
        uint4 rv = *(const uint4*)(feat + (size_t)d * 256 + f0);
        den += p;
        float2 t0 = bf2_to_f32(rv.x), t1 = bf2_to_f32(rv.y);
        float2 t2 = bf2_to_f32(rv.z), t3 = bf2_to_f32(rv.w);
        acc[0] += p * t0.x; acc[1] += p * t0.y; acc[2] += p * t1.x; acc[3] += p * t1.y;
        acc[4] += p * t2.x; acc[5] += p * t2.y; acc[6] += p * t3.x; acc[7] += p * t3.y;
    }
    aggr2_range(csr_src, rs, 0, nLo, feat, a_s, adh, f0, half, den, acc);  // phase A
    aggr2_range(csr_src, rs, nLo, n, feat, a_s, adh, f0, half, den, acc);  // phase B

    den += __shfl_xor(den, 32);
    #pragma unroll
    for (int k = 0; k < 8; ++k) acc[k] += __shfl_xor(acc[k], 32);

    float inv = 1.f / den;
    if (half == 0) {
        float4 b0 = *(const float4*)(bias + f0);
        float4 b1 = *(const float4*)(bias + f0 + 4);
        f32x4 o0, o1;
        o0.x = acc[0] * inv + b0.x; o0.y = acc[1] * inv + b0.y;
        o0.z = acc[2] * inv + b0.z; o0.w = acc[3] * inv + b0.w;
        o1.x = acc[4] * inv + b1.x; o1.y = acc[5] * inv + b1.y;
        o1.z = acc[6] * inv + b1.z; o1.w = acc[7] * inv + b1.w;
        __builtin_nontemporal_store(o0, (f32x4*)(out + (size_t)d * 256 + f0));
        __builtin_nontemporal_store(o1, (f32x4*)(out + (size_t)d * 256 + f0 + 4));
    }
}

extern "C" void kernel_launch(void* const* d_in, const int* in_sizes, int n_in,
                              void* d_out, int out_size, void* d_ws, size_t ws_size,
                              hipStream_t stream)
{
    const int*   ei     = (const int*)  d_in[0];
    const float* x      = (const float*)d_in[1];
    const float* ln_w   = (const float*)d_in[2];
    const float* ln_b   = (const float*)d_in[3];
    const float* W1     = (const float*)d_in[4];
    const float* att_s1 = (const float*)d_in[5];
    const float* att_d1 = (const float*)d_in[6];
    const float* b1     = (const float*)d_in[7];
    const float* W2     = (const float*)d_in[8];
    const float* att_s2 = (const float*)d_in[9];
    const float* att_d2 = (const float*)d_in[10];
    const float* b2     = (const float*)d_in[11];
    float* out = (float*)d_out;

    short* h0b = (short*)d_ws;                // [50000,256] bf16 LN out
    short* h1b = h0b + 12800000;              // [50000,512] bf16 gemm1 out
    short* h2b = h1b + 25600000;              // [50000,512] bf16 conv1 out
    short* h3b = h2b + 25600000;              // [50000,256] bf16 gemm2 out
    short* W1T = h3b + 12800000;              // [512,256] bf16
    short* W2T = W1T + 131072;                // [256,512] bf16
    float* a_s1 = (float*)(W2T + 131072);     // [50000,8]
    float* a_d1 = a_s1 + 400000;
    // zero-init region (single memset): a_s2, a_d2, cnt, cnt_lo, cur_lo, cur_hi, cursor
    float* a_s2 = a_d1 + 400000;              // [50000]
    float* a_d2 = a_s2 + 50000;               // [50000]
    int* cnt     = (int*)(a_d2 + 50000);      // 50000
    int* cnt_lo  = cnt + 50000;               // 50000
    int* cur_lo  = cnt_lo + 50000;            // 50000
    int* cur_hi  = cur_lo + 50000;            // 50000
    int* cursor  = cur_hi + 50000;            // 1
    int* row_start = cursor + 1;              // 50000
    int* csr_src   = row_start + 50000;       // 500000

    // one memset zeroes a_s2..cursor (300001 words)
    hipMemsetAsync(a_s2, 0, 300001 * 4, stream);

    // fused LN + count (+low-source count) + weight transposes
    prep_kernel<<<15478, 256, 0, stream>>>(x, ln_w, ln_b, h0b, ei, cnt, cnt_lo,
                                           W1, W1T, W2, W2T);
    alloc_kernel<<<196, 256, 0, stream>>>(cnt, row_start, cursor);

    // --- conv1: gemm1 (+fused dots1, plain stores) + partitioned CSR-fill tail ---
    constexpr int NG1 = 391 * 4;   // 1564 gemm blocks
    gemm_mfma<512, 256, 64, true><<<NG1 + 1954, 256, 0, stream>>>(
        h0b, W1T, h1b, att_s1, att_d1, a_s1, a_d1, N_ENT, NG1,
        ei, row_start, cnt_lo, cur_lo, cur_hi, csr_src);
    aggr1_kernel<<<12500, 256, 0, stream>>>(csr_src, row_start, cnt, cnt_lo,
                                            h1b, a_s1, a_d1, b1, h2b);

    // --- conv2: gemm2 (+fused dots2 via atomics) ---
    constexpr int NG2 = 391 * 2;   // 782 gemm blocks
    gemm_mfma<256, 512, 256, false><<<NG2, 256, 0, stream>>>(
        h2b, W2T, h3b, att_s2, att_d2, a_s2, a_d2, N_ENT, NG2,
        nullptr, nullptr, nullptr, nullptr, nullptr, nullptr);
    aggr2_kernel<<<12500, 256, 0, stream>>>(csr_src, row_start, cnt, cnt_lo,
                                            h3b, a_s2, a_d2, b2, out);
}